// Round 1
// baseline (97.136 us; speedup 1.0000x reference)
//
#include <hip/hip_runtime.h>
#include <hip/hip_bf16.h>

// Analytic collapse of the 4-qubit circuit:
//   out = psi(theta)^T A psi(theta),  A = Re(U^dag Z0 U)  (U fixed by weights)
// expanded into an 81-coefficient multilinear polynomial in {1,cos,sin} per angle.

__global__ void qconv_setup(const float* __restrict__ wts, float* __restrict__ W) {
    __shared__ float2 U[16][16];   // U[col][i]: column col of the circuit unitary
    __shared__ float  A[16][16];
    int tid = threadIdx.x;

    if (tid < 16) {
        float2* v = U[tid];
        for (int i = 0; i < 16; ++i) v[i] = make_float2(i == tid ? 1.f : 0.f, 0.f);

        for (int layer = 0; layer < 2; ++layer) {
            for (int q = 0; q < 4; ++q) {
                int p = 3 - q;                       // wire q -> bit (3-q), wire 0 most significant
                float thx = wts[(layer * 4 + q) * 3 + 0];
                float thy = wts[(layer * 4 + q) * 3 + 1];
                float thz = wts[(layer * 4 + q) * 3 + 2];
                // RX(thx): [[c, -i s], [-i s, c]]
                {
                    float c = cosf(0.5f * thx), s = sinf(0.5f * thx);
                    for (int i = 0; i < 16; ++i) if (!((i >> p) & 1)) {
                        int j = i | (1 << p);
                        float2 a = v[i], b = v[j];
                        v[i] = make_float2(c * a.x + s * b.y, c * a.y - s * b.x);
                        v[j] = make_float2(c * b.x + s * a.y, c * b.y - s * a.x);
                    }
                }
                // RY(thy): [[c, -s], [s, c]]
                {
                    float c = cosf(0.5f * thy), s = sinf(0.5f * thy);
                    for (int i = 0; i < 16; ++i) if (!((i >> p) & 1)) {
                        int j = i | (1 << p);
                        float2 a = v[i], b = v[j];
                        v[i] = make_float2(c * a.x - s * b.x, c * a.y - s * b.y);
                        v[j] = make_float2(s * a.x + c * b.x, s * a.y + c * b.y);
                    }
                }
                // RZ(thz): diag(e^{-i t/2}, e^{+i t/2})
                {
                    float c = cosf(0.5f * thz), s = sinf(0.5f * thz);
                    for (int i = 0; i < 16; ++i) {
                        float2 a = v[i];
                        if (!((i >> p) & 1)) v[i] = make_float2(c * a.x + s * a.y, c * a.y - s * a.x);
                        else                 v[i] = make_float2(c * a.x - s * a.y, c * a.y + s * a.x);
                    }
                }
            }
            // CNOT(0,1), CNOT(2,3), CNOT(0,2), CNOT(1,3)
            const int cn[4][2] = {{0,1},{2,3},{0,2},{1,3}};
            for (int e = 0; e < 4; ++e) {
                int pc = 3 - cn[e][0], pt = 3 - cn[e][1];
                for (int i = 0; i < 16; ++i) if (((i >> pc) & 1) && !((i >> pt) & 1)) {
                    int j = i | (1 << pt);
                    float2 t = v[i]; v[i] = v[j]; v[j] = t;
                }
            }
        }
    }
    __syncthreads();

    // A[j][k] = Re( sum_i conj(U[i][j]) z_i U[i][k] ),  z_i = (i&8) ? -1 : +1
    {
        int j = tid >> 4, k = tid & 15;
        float re = 0.f;
        for (int i = 0; i < 16; ++i) {
            float z = (i & 8) ? -1.f : 1.f;
            float2 a = U[j][i], b = U[k][i];
            re += z * (a.x * b.x + a.y * b.y);
        }
        A[j][k] = re;
    }
    __syncthreads();

    // Project quadratic form onto the {1, cos, sin}^4 basis: 81 coefficients.
    // per-qubit factor of psi_j psi_k:
    //   (0,0): 1/2 + 1/2 cos ; (1,1): 1/2 - 1/2 cos ; (0,1)/(1,0): 1/2 sin
    if (tid < 81) {
        int e = tid;
        int ee[4] = { e / 27, (e / 9) % 3, (e / 3) % 3, e % 3 };
        float sum = 0.f;
        for (int j = 0; j < 16; ++j) {
            for (int k = 0; k < 16; ++k) {
                float prod = A[j][k];
                for (int q = 0; q < 4; ++q) {
                    int bj = (j >> (3 - q)) & 1, bk = (k >> (3 - q)) & 1;
                    int eq = ee[q];
                    float m;
                    if (eq == 0)      m = (bj == bk) ? 0.5f : 0.f;
                    else if (eq == 1) m = (bj == bk) ? (bj ? -0.5f : 0.5f) : 0.f;
                    else              m = (bj != bk) ? 0.5f : 0.f;
                    prod *= m;
                }
                sum += prod;
            }
        }
        W[e] = sum;
    }
}

__global__ __launch_bounds__(256) void qconv_main(
        const float* __restrict__ x, const float* __restrict__ Wc,
        float* __restrict__ out, int total) {
    // Hoist the 81 wave-uniform coefficients into registers once per thread.
    float w[81];
    #pragma unroll
    for (int i = 0; i < 81; ++i) w[i] = Wc[i];

    const int WD = 127;
    int stride = gridDim.x * blockDim.x;
    for (int n = blockIdx.x * blockDim.x + threadIdx.x; n < total; n += stride) {
        int wq  = n % WD;
        int r   = n / WD;
        int h   = r % WD;
        int img = r / WD;
        int base = (img * 128 + h) * 128 + wq;

        float t0 = x[base], t1 = x[base + 1], t2 = x[base + 128], t3 = x[base + 129];
        float s0, c0, s1, c1, s2, c2, s3, c3;
        __sincosf(t0, &s0, &c0);
        __sincosf(t1, &s1, &c1);
        __sincosf(t2, &s2, &c2);
        __sincosf(t3, &s3, &c3);

        float u0[3] = {1.f, c0, s0};
        float u1[3] = {1.f, c1, s1};
        float u2[3] = {1.f, c2, s2};

        float ev = 0.f;
        #pragma unroll
        for (int e0 = 0; e0 < 3; ++e0) {
            float a0 = 0.f;
            #pragma unroll
            for (int e1 = 0; e1 < 3; ++e1) {
                float a1 = 0.f;
                #pragma unroll
                for (int e2 = 0; e2 < 3; ++e2) {
                    const int idx = ((e0 * 3 + e1) * 3 + e2) * 3;
                    float a2 = w[idx] + w[idx + 1] * c3 + w[idx + 2] * s3;
                    a1 += a2 * u2[e2];
                }
                a0 += a1 * u1[e1];
            }
            ev += a0 * u0[e0];
        }
        out[n] = ev;
    }
}

extern "C" void kernel_launch(void* const* d_in, const int* in_sizes, int n_in,
                              void* d_out, int out_size, void* d_ws, size_t ws_size,
                              hipStream_t stream) {
    const float* x   = (const float*)d_in[0];
    const float* wts = (const float*)d_in[1];
    float* out = (float*)d_out;
    float* W   = (float*)d_ws;   // 81 floats

    qconv_setup<<<1, 256, 0, stream>>>(wts, W);

    int total = out_size;        // 32*3*127*127
    int blocks = 2048;
    qconv_main<<<blocks, 256, 0, stream>>>(x, W, out, total);
}

// Round 2
// 16.877 us; speedup vs baseline: 5.7555x; 5.7555x over previous
//
#include <hip/hip_runtime.h>
#include <hip/hip_bf16.h>

// Analytic collapse of the 4-qubit circuit:
//   out = psi(theta)^T A psi(theta),  A = Re(U^dag Z0 U)  (U fixed by weights)
// expanded into an 81-coefficient multilinear polynomial in {1,cos,sin} per angle.
//
// Setup kernel: 16 threads simulate the 16 basis columns of U entirely in
// registers (all loops unrolled -> compile-time indices -> VGPRs), then 256
// threads form A = Re(U^dag Z0 U), then 81 threads project onto the
// {1,cos,sin}^4 basis using the exact sparsity of the projector:
//   W[e] = (1/16) * sum_{b in {0,1}^4} sign(b,e) * A[b][b ^ mask2(e)]
// where mask2 = qubits with 'sin' digit, sign = parity(b & mask1), mask1 =
// qubits with 'cos-with-sign' digit (the (1-cos)/2 branch).

__global__ void qconv_setup(const float* __restrict__ wts, float* __restrict__ W) {
    __shared__ float2 U[16][16];   // U[col][i]
    __shared__ float  A[16][16];
    const int tid = threadIdx.x;

    if (tid < 16) {
        float2 v[16];
        #pragma unroll
        for (int i = 0; i < 16; ++i) v[i] = make_float2(i == tid ? 1.f : 0.f, 0.f);

        #pragma unroll
        for (int layer = 0; layer < 2; ++layer) {
            #pragma unroll
            for (int q = 0; q < 4; ++q) {
                const int p = 3 - q;                 // wire q -> bit (3-q)
                const float thx = wts[(layer * 4 + q) * 3 + 0];
                const float thy = wts[(layer * 4 + q) * 3 + 1];
                const float thz = wts[(layer * 4 + q) * 3 + 2];
                // RX: [[c, -i s], [-i s, c]]
                {
                    float c = __cosf(0.5f * thx), s = __sinf(0.5f * thx);
                    #pragma unroll
                    for (int i = 0; i < 16; ++i) if (!((i >> p) & 1)) {
                        const int j = i | (1 << p);
                        float2 a = v[i], b = v[j];
                        v[i] = make_float2(c * a.x + s * b.y, c * a.y - s * b.x);
                        v[j] = make_float2(c * b.x + s * a.y, c * b.y - s * a.x);
                    }
                }
                // RY: [[c, -s], [s, c]]
                {
                    float c = __cosf(0.5f * thy), s = __sinf(0.5f * thy);
                    #pragma unroll
                    for (int i = 0; i < 16; ++i) if (!((i >> p) & 1)) {
                        const int j = i | (1 << p);
                        float2 a = v[i], b = v[j];
                        v[i] = make_float2(c * a.x - s * b.x, c * a.y - s * b.y);
                        v[j] = make_float2(s * a.x + c * b.x, s * a.y + c * b.y);
                    }
                }
                // RZ: diag(e^{-i t/2}, e^{+i t/2})
                {
                    float c = __cosf(0.5f * thz), s = __sinf(0.5f * thz);
                    #pragma unroll
                    for (int i = 0; i < 16; ++i) {
                        float2 a = v[i];
                        if (!((i >> p) & 1)) v[i] = make_float2(c * a.x + s * a.y, c * a.y - s * a.x);
                        else                 v[i] = make_float2(c * a.x - s * a.y, c * a.y + s * a.x);
                    }
                }
            }
            // CNOT(0,1), CNOT(2,3), CNOT(0,2), CNOT(1,3)
            #pragma unroll
            for (int ee = 0; ee < 4; ++ee) {
                const int cc[4] = {0, 2, 0, 1}, tt[4] = {1, 3, 2, 3};
                const int pc = 3 - cc[ee], pt = 3 - tt[ee];
                #pragma unroll
                for (int i = 0; i < 16; ++i) if (((i >> pc) & 1) && !((i >> pt) & 1)) {
                    const int j = i | (1 << pt);
                    float2 t = v[i]; v[i] = v[j]; v[j] = t;
                }
            }
        }
        #pragma unroll
        for (int i = 0; i < 16; ++i) U[tid][i] = v[i];
    }
    __syncthreads();

    // A[j][k] = Re( sum_i conj(U[i][j]) z_i U[i][k] ),  z_i = (i&8) ? -1 : +1
    {
        const int j = tid >> 4, k = tid & 15;
        float re = 0.f;
        #pragma unroll
        for (int i = 0; i < 16; ++i) {
            const float z = (i & 8) ? -1.f : 1.f;
            float2 a = U[j][i], b = U[k][i];
            re += z * (a.x * b.x + a.y * b.y);
        }
        A[j][k] = re;
    }
    __syncthreads();

    if (tid < 81) {
        const int e = tid;
        const int d0 = e / 27, d1 = (e / 9) % 3, d2 = (e / 3) % 3, d3 = e % 3;
        int mask1 = 0, mask2 = 0;
        if (d0 == 1) mask1 |= 8; else if (d0 == 2) mask2 |= 8;
        if (d1 == 1) mask1 |= 4; else if (d1 == 2) mask2 |= 4;
        if (d2 == 1) mask1 |= 2; else if (d2 == 2) mask2 |= 2;
        if (d3 == 1) mask1 |= 1; else if (d3 == 2) mask2 |= 1;
        float sum = 0.f;
        #pragma unroll
        for (int b = 0; b < 16; ++b) {
            const float sgn = (__popc(b & mask1) & 1) ? -1.f : 1.f;
            sum += sgn * A[b][b ^ mask2];
        }
        W[e] = sum * 0.0625f;
    }
}

// Main kernel: each thread owns up to 4 consecutive outputs in one image row.
// 10 sincos cover 4 outputs (sliding 2x2 window); coefficient tensor loaded
// once per thread as dwordx4 and amortized over the 4 outputs.
__global__ __launch_bounds__(256) void qconv_main(
        const float* __restrict__ x, const float* __restrict__ Wc,
        float* __restrict__ out, int rows) {
    const int g   = blockIdx.x * blockDim.x + threadIdx.x;
    const int row = g >> 5;           // image-row pair index: img*127 + h
    const int l   = g & 31;           // chunk within row
    if (row >= rows) return;

    float w[81];
    {
        const float4* W4 = (const float4*)Wc;
        #pragma unroll
        for (int i = 0; i < 20; ++i) {
            float4 v4 = W4[i];
            w[4*i+0] = v4.x; w[4*i+1] = v4.y; w[4*i+2] = v4.z; w[4*i+3] = v4.w;
        }
        w[80] = Wc[80];
    }

    const int img   = row / 127;
    const int h     = row % 127;
    const int col0  = l * 4;                  // l=31 -> cols 124..126 (3 outputs)
    const int ncols = (l == 31) ? 3 : 4;
    const int base  = img * 16384 + h * 128 + col0;   // 16B-aligned

    float tp[5], bt[5];
    {
        float4 t4 = *(const float4*)(x + base);
        float4 b4 = *(const float4*)(x + base + 128);
        tp[0] = t4.x; tp[1] = t4.y; tp[2] = t4.z; tp[3] = t4.w;
        bt[0] = b4.x; bt[1] = b4.y; bt[2] = b4.z; bt[3] = b4.w;
        tp[4] = 0.f; bt[4] = 0.f;
        if (ncols == 4) { tp[4] = x[base + 4]; bt[4] = x[base + 132]; }
    }

    float ct[5], st[5], cb[5], sb[5];
    #pragma unroll
    for (int j = 0; j < 5; ++j) {
        __sincosf(tp[j], &st[j], &ct[j]);
        __sincosf(bt[j], &sb[j], &cb[j]);
    }

    float ev[4];
    #pragma unroll
    for (int k = 0; k < 4; ++k) {
        const float c0 = ct[k],     s0 = st[k];
        const float c1 = ct[k + 1], s1 = st[k + 1];
        const float c2 = cb[k],     s2 = sb[k];
        const float c3 = cb[k + 1], s3 = sb[k + 1];
        float acc = 0.f;
        #pragma unroll
        for (int e0 = 0; e0 < 3; ++e0) {
            const float u0 = (e0 == 0) ? 1.f : ((e0 == 1) ? c0 : s0);
            float a0 = 0.f;
            #pragma unroll
            for (int e1 = 0; e1 < 3; ++e1) {
                const float u1 = (e1 == 0) ? 1.f : ((e1 == 1) ? c1 : s1);
                float a1 = 0.f;
                #pragma unroll
                for (int e2 = 0; e2 < 3; ++e2) {
                    const float u2 = (e2 == 0) ? 1.f : ((e2 == 1) ? c2 : s2);
                    const int idx = ((e0 * 3 + e1) * 3 + e2) * 3;
                    const float a2 = w[idx] + w[idx + 1] * c3 + w[idx + 2] * s3;
                    a1 += a2 * u2;
                }
                a0 += a1 * u1;
            }
            acc += a0 * u0;
        }
        ev[k] = acc;
    }

    const int obase = row * 127 + col0;
    #pragma unroll
    for (int k = 0; k < 4; ++k) if (k < ncols) out[obase + k] = ev[k];
}

extern "C" void kernel_launch(void* const* d_in, const int* in_sizes, int n_in,
                              void* d_out, int out_size, void* d_ws, size_t ws_size,
                              hipStream_t stream) {
    const float* x   = (const float*)d_in[0];
    const float* wts = (const float*)d_in[1];
    float* out = (float*)d_out;
    float* W   = (float*)d_ws;   // 81 floats

    qconv_setup<<<1, 256, 0, stream>>>(wts, W);

    const int rows    = out_size / 127;       // 32*3*127 = 12192
    const int threads = rows * 32;            // 32 chunks per row
    const int blocks  = (threads + 255) / 256;
    qconv_main<<<blocks, 256, 0, stream>>>(x, W, out, rows);
}

// Round 3
// 16.062 us; speedup vs baseline: 6.0474x; 1.0507x over previous
//
#include <hip/hip_runtime.h>
#include <hip/hip_bf16.h>

// Fully-fused analytic collapse of the 4-qubit circuit:
//   out = psi(theta)^T A psi(theta),  A = Re(U^dag Z0 U)  (U fixed by weights)
// expanded into an 81-coefficient multilinear polynomial in {1,cos,sin} per angle.
// ONE kernel: each block redundantly computes the 81 coefficients (cheap,
// overlapped across blocks), then evaluates the polynomial for its tile.
// Thread tile: 4 cols x 2 output rows (3 input rows) -> sincos reuse of the
// middle row and 8-output amortization of the coefficient register load.

__device__ __forceinline__ void compute_W_block(const float* __restrict__ wts,
                                                float* __restrict__ Wsh) {
    __shared__ float2 U[16][16];   // U[col][i]
    __shared__ float  A[16][16];
    const int tid = threadIdx.x;

    if (tid < 16) {
        float2 v[16];
        #pragma unroll
        for (int i = 0; i < 16; ++i) v[i] = make_float2(i == tid ? 1.f : 0.f, 0.f);

        #pragma unroll
        for (int layer = 0; layer < 2; ++layer) {
            #pragma unroll
            for (int q = 0; q < 4; ++q) {
                const int p = 3 - q;                 // wire q -> bit (3-q)
                const float thx = wts[(layer * 4 + q) * 3 + 0];
                const float thy = wts[(layer * 4 + q) * 3 + 1];
                const float thz = wts[(layer * 4 + q) * 3 + 2];
                // RX: [[c, -i s], [-i s, c]]
                {
                    float c = __cosf(0.5f * thx), s = __sinf(0.5f * thx);
                    #pragma unroll
                    for (int i = 0; i < 16; ++i) if (!((i >> p) & 1)) {
                        const int j = i | (1 << p);
                        float2 a = v[i], b = v[j];
                        v[i] = make_float2(c * a.x + s * b.y, c * a.y - s * b.x);
                        v[j] = make_float2(c * b.x + s * a.y, c * b.y - s * a.x);
                    }
                }
                // RY: [[c, -s], [s, c]]
                {
                    float c = __cosf(0.5f * thy), s = __sinf(0.5f * thy);
                    #pragma unroll
                    for (int i = 0; i < 16; ++i) if (!((i >> p) & 1)) {
                        const int j = i | (1 << p);
                        float2 a = v[i], b = v[j];
                        v[i] = make_float2(c * a.x - s * b.x, c * a.y - s * b.y);
                        v[j] = make_float2(s * a.x + c * b.x, s * a.y + c * b.y);
                    }
                }
                // RZ: diag(e^{-i t/2}, e^{+i t/2})
                {
                    float c = __cosf(0.5f * thz), s = __sinf(0.5f * thz);
                    #pragma unroll
                    for (int i = 0; i < 16; ++i) {
                        float2 a = v[i];
                        if (!((i >> p) & 1)) v[i] = make_float2(c * a.x + s * a.y, c * a.y - s * a.x);
                        else                 v[i] = make_float2(c * a.x - s * a.y, c * a.y + s * a.x);
                    }
                }
            }
            // CNOT(0,1), CNOT(2,3), CNOT(0,2), CNOT(1,3)
            #pragma unroll
            for (int ee = 0; ee < 4; ++ee) {
                const int cc[4] = {0, 2, 0, 1}, tt[4] = {1, 3, 2, 3};
                const int pc = 3 - cc[ee], pt = 3 - tt[ee];
                #pragma unroll
                for (int i = 0; i < 16; ++i) if (((i >> pc) & 1) && !((i >> pt) & 1)) {
                    const int j = i | (1 << pt);
                    float2 t = v[i]; v[i] = v[j]; v[j] = t;
                }
            }
        }
        #pragma unroll
        for (int i = 0; i < 16; ++i) U[tid][i] = v[i];
    }
    __syncthreads();

    // A[j][k] = Re( sum_i conj(U[i][j]) z_i U[i][k] ),  z_i = (i&8) ? -1 : +1
    {
        const int j = tid >> 4, k = tid & 15;
        float re = 0.f;
        #pragma unroll
        for (int i = 0; i < 16; ++i) {
            const float z = (i & 8) ? -1.f : 1.f;
            float2 a = U[j][i], b = U[k][i];
            re += z * (a.x * b.x + a.y * b.y);
        }
        A[j][k] = re;
    }
    __syncthreads();

    // Project onto {1,cos,sin}^4 using exact projector sparsity:
    //   W[e] = (1/16) * sum_b parity(b&mask1) * A[b][b^mask2]
    if (tid < 84) {
        float r = 0.f;
        if (tid < 81) {
            const int e = tid;
            const int d0 = e / 27, d1 = (e / 9) % 3, d2 = (e / 3) % 3, d3 = e % 3;
            int mask1 = 0, mask2 = 0;
            if (d0 == 1) mask1 |= 8; else if (d0 == 2) mask2 |= 8;
            if (d1 == 1) mask1 |= 4; else if (d1 == 2) mask2 |= 4;
            if (d2 == 1) mask1 |= 2; else if (d2 == 2) mask2 |= 2;
            if (d3 == 1) mask1 |= 1; else if (d3 == 2) mask2 |= 1;
            float sum = 0.f;
            #pragma unroll
            for (int b = 0; b < 16; ++b) {
                const float sgn = (__popc(b & mask1) & 1) ? -1.f : 1.f;
                sum += sgn * A[b][b ^ mask2];
            }
            r = sum * 0.0625f;
        }
        Wsh[tid] = r;
    }
    __syncthreads();
}

__global__ __launch_bounds__(256) void qconv_fused(
        const float* __restrict__ x, const float* __restrict__ wts,
        float* __restrict__ out) {
    __shared__ __align__(16) float Wsh[84];
    compute_W_block(wts, Wsh);

    // Hoist coefficients LDS -> registers (ds_read_b128), amortized over 8 outputs.
    float w[81];
    {
        const float4* W4 = (const float4*)Wsh;
        #pragma unroll
        for (int i = 0; i < 20; ++i) {
            float4 v4 = W4[i];
            w[4*i+0] = v4.x; w[4*i+1] = v4.y; w[4*i+2] = v4.z; w[4*i+3] = v4.w;
        }
        w[80] = Wsh[80];
    }

    // group = (img, row-pair); 32 lanes x 4 cols cover one 127-wide row pair
    const int g    = blockIdx.x * 8 + (threadIdx.x >> 5);   // 0..6143
    const int l    = threadIdx.x & 31;
    const int img  = g >> 6;                                // /64
    const int pair = g & 63;
    const int h    = pair * 2;
    const int nr   = (pair == 63) ? 1 : 2;                  // output rows in this group
    const int col0 = l * 4;
    const int ncols = (l == 31) ? 3 : 4;
    const int base = img * 16384 + h * 128 + col0;          // 16B-aligned

    float r0[5], r1[5], r2[5];
    {
        float4 a4 = *(const float4*)(x + base);
        float4 b4 = *(const float4*)(x + base + 128);
        r0[0]=a4.x; r0[1]=a4.y; r0[2]=a4.z; r0[3]=a4.w;
        r1[0]=b4.x; r1[1]=b4.y; r1[2]=b4.z; r1[3]=b4.w;
        r0[4]=0.f; r1[4]=0.f; r2[0]=0.f; r2[1]=0.f; r2[2]=0.f; r2[3]=0.f; r2[4]=0.f;
        if (ncols == 4) { r0[4] = x[base + 4]; r1[4] = x[base + 132]; }
        if (nr == 2) {
            float4 c4 = *(const float4*)(x + base + 256);
            r2[0]=c4.x; r2[1]=c4.y; r2[2]=c4.z; r2[3]=c4.w;
            if (ncols == 4) r2[4] = x[base + 260];
        }
    }

    float c0a[5], s0a[5], c1a[5], s1a[5], c2a[5], s2a[5];
    #pragma unroll
    for (int j = 0; j < 5; ++j) {
        __sincosf(r0[j], &s0a[j], &c0a[j]);
        __sincosf(r1[j], &s1a[j], &c1a[j]);
        __sincosf(r2[j], &s2a[j], &c2a[j]);
    }

    // eval(top-left, top-right, bottom-left, bottom-right)
    auto eval = [&](float c0, float s0, float c1, float s1,
                    float c2, float s2, float c3, float s3) -> float {
        float acc = 0.f;
        #pragma unroll
        for (int e0 = 0; e0 < 3; ++e0) {
            const float u0 = (e0 == 0) ? 1.f : ((e0 == 1) ? c0 : s0);
            float a0 = 0.f;
            #pragma unroll
            for (int e1 = 0; e1 < 3; ++e1) {
                const float u1 = (e1 == 0) ? 1.f : ((e1 == 1) ? c1 : s1);
                float a1 = 0.f;
                #pragma unroll
                for (int e2 = 0; e2 < 3; ++e2) {
                    const float u2 = (e2 == 0) ? 1.f : ((e2 == 1) ? c2 : s2);
                    const int idx = ((e0 * 3 + e1) * 3 + e2) * 3;
                    const float a2 = w[idx] + w[idx + 1] * c3 + w[idx + 2] * s3;
                    a1 += a2 * u2;
                }
                a0 += a1 * u1;
            }
            acc += a0 * u0;
        }
        return acc;
    };

    float ev0[4], ev1[4];
    #pragma unroll
    for (int k = 0; k < 4; ++k) {
        ev0[k] = eval(c0a[k], s0a[k], c0a[k+1], s0a[k+1],
                      c1a[k], s1a[k], c1a[k+1], s1a[k+1]);
        ev1[k] = eval(c1a[k], s1a[k], c1a[k+1], s1a[k+1],
                      c2a[k], s2a[k], c2a[k+1], s2a[k+1]);
    }

    const int ob0 = (img * 127 + h) * 127 + col0;
    #pragma unroll
    for (int k = 0; k < 4; ++k) if (k < ncols) out[ob0 + k] = ev0[k];
    if (nr == 2) {
        const int ob1 = ob0 + 127;
        #pragma unroll
        for (int k = 0; k < 4; ++k) if (k < ncols) out[ob1 + k] = ev1[k];
    }
}

extern "C" void kernel_launch(void* const* d_in, const int* in_sizes, int n_in,
                              void* d_out, int out_size, void* d_ws, size_t ws_size,
                              hipStream_t stream) {
    const float* x   = (const float*)d_in[0];
    const float* wts = (const float*)d_in[1];
    float* out = (float*)d_out;

    // 96 images x 64 row-pair groups, 8 groups per 256-thread block
    const int blocks = (96 * 64) / 8;   // 768
    qconv_fused<<<blocks, 256, 0, stream>>>(x, wts, out);
}